// Round 7
// baseline (1929.452 us; speedup 1.0000x reference)
//
#include <hip/hip_runtime.h>
#include <cmath>

#define CC 21
#define HH 512
#define WW 512
#define HWSZ (HH*WW)
#define CHW (CC*HWSZ)
#define NITERS 5
#define PBLOCKS 1024          // partial-reduction width (blocks of init_sm/final)
#define ROWF (CC*WW)          // 10752 floats per image row in HWC
#define HROWF (CC*256)        // 5376 floats per half row

struct K9 { float k[9]; };

__device__ __forceinline__ float bf16_to_f(unsigned short v) {
    unsigned int u = ((unsigned int)v) << 16;
    union { unsigned int i; float f; } cv; cv.i = u; return cv.f;
}
__device__ __forceinline__ unsigned short f_to_bf16(float f) {
    union { float f; unsigned int i; } cv; cv.f = f;
    unsigned int b = cv.i + 0x7FFFu + ((cv.i >> 16) & 1u);   // RNE
    return (unsigned short)(b >> 16);
}

// spT[h*W + w] = sp_map[w*W + h]  (one-time; coalesced mask reads later)
__global__ void transpose_sp_kernel(const int* __restrict__ sp, int* __restrict__ spT) {
    int p = blockIdx.x*256 + threadIdx.x;
    int h = p >> 9, w = p & (WW - 1);
    spT[p] = sp[w*WW + h];
}

// M = CM @ (SKW + BKW)   (both blurs identical since theta_gamma==theta_beta)
__global__ void precomp_M_kernel(const float* __restrict__ skw, const float* __restrict__ bkw,
                                 const float* __restrict__ cm, float* __restrict__ M) {
    int i = blockIdx.x * blockDim.x + threadIdx.x;
    if (i >= CC*CC) return;
    int r = i / CC, k = i - r*CC;
    float a = 0.f;
    for (int j = 0; j < CC; ++j) a += cm[r*CC + j] * (skw[j*CC + k] + bkw[j*CC + k]);
    M[i] = a;
}

// iter-0: sm0 = softmax(u) from LDS-staged unaries half-row + clique partials.
// part layout SLOT-MAJOR: part[t*PBLOCKS + b]; t: 0..20 s1, 21..41 s2, 42 n1, 43 n2
__launch_bounds__(256)
__global__ void init_sm_kernel(const float* __restrict__ unaries, float* __restrict__ sm,
                               const int* __restrict__ spT,
                               const int* __restrict__ sp_indices,
                               float* __restrict__ part) {
    __shared__ __align__(16) float lu[HROWF];
    __shared__ float acc[44];
    int bid = blockIdx.x;
    int h = bid >> 1, w0 = (bid & 1) << 8;
    int tx = threadIdx.x;
    if (tx < 44) acc[tx] = 0.f;
    {
        const float4* src = (const float4*)(unaries + (size_t)h*ROWF + w0*CC);
        float4* dst = (float4*)lu;
        #pragma unroll
        for (int j = 0; j < 6; ++j) {
            int idx = j*256 + tx;
            if (idx < HROWF/4) dst[idx] = src[idx];
        }
    }
    __syncthreads();
    int p = h*WW + w0 + tx;
    float v[CC]; float m = -1e30f;
    #pragma unroll
    for (int c = 0; c < CC; ++c) { v[c] = lu[tx*CC + c]; m = fmaxf(m, v[c]); }
    float s = 0.f;
    #pragma unroll
    for (int c = 0; c < CC; ++c) { v[c] = expf(v[c] - m); s += v[c]; }
    float inv = 1.f / s;
    #pragma unroll
    for (int c = 0; c < CC; ++c) { v[c] *= inv; sm[(size_t)c*HWSZ + p] = v[c]; }

    int idx = sp_indices[0];
    int lab = spT[p];
    if (lab == idx || lab == idx + 1) {
        int mk = (lab == idx) ? 0 : 1;
        atomicAdd(&acc[42 + mk], 1.f);
        for (int c = 0; c < CC; ++c) atomicAdd(&acc[mk*21 + c], expf(v[c]));
    }
    __syncthreads();
    if (tx < 44) part[tx*PBLOCKS + bid] = acc[tx];
}

// 42 blocks; block t sums slot t and count slot 42+(t/21), coalesced.
__launch_bounds__(256)
__global__ void finalize_kernel(const float* __restrict__ part, float* __restrict__ B) {
    __shared__ float rs[256], rn[256];
    int t = blockIdx.x;          // 0..41
    int m = t / 21;
    int tid = threadIdx.x;
    float s = 0.f, n = 0.f;
    for (int b = tid; b < PBLOCKS; b += 256) {
        s += part[t*PBLOCKS + b];
        n += part[(42 + m)*PBLOCKS + b];
    }
    rs[tid] = s; rn[tid] = n;
    __syncthreads();
    for (int off = 128; off > 0; off >>= 1) {
        if (tid < off) { rs[tid] += rs[tid+off]; rn[tid] += rn[tid+off]; }
        __syncthreads();
    }
    if (tid == 0) B[t] = logf((float)HWSZ - rn[0] + rs[0]);
}

// vertical 9-tap blur, zero pad. Half-row blocks, XCD-chunked rows.
__launch_bounds__(256)
__global__ void vblur_kernel(const float* __restrict__ sm, float* __restrict__ tmp, K9 kk) {
    int bid = blockIdx.x;
    int c = bid >> 10;                 // 1024 half-rows per plane
    int r = bid & 1023;
    int xcd = r & 7, tt = r >> 3;
    int h  = xcd*64 + (tt >> 1);
    int w0 = (tt & 1) << 8;
    int w  = w0 + threadIdx.x;
    const float* col = sm + (size_t)c*HWSZ + w;
    float acc = 0.f;
    #pragma unroll
    for (int t = 0; t < 9; ++t) {
        int hh = h + t - 4;
        if (hh >= 0 && hh < HH) acc += kk.k[t] * col[hh*WW];
    }
    tmp[(size_t)c*HWSZ + h*WW + w] = acc;
}

// Fused: hblur (LDS tile from tmp) -> /norm -> M@ -> attachment -> q_new,
// then softmax(q_new) written IN-PLACE over sm (own-pixel only) + partials
// for the NEXT iteration's B. Last iter: q_new -> out HWC via tile reuse.
__launch_bounds__(256, 4)
__global__ void final_kernel(const float* __restrict__ tmp, float* sm,
                             float* __restrict__ outHWC,
                             const float* __restrict__ unaries,
                             const int* __restrict__ spT,
                             const int* __restrict__ sp_indices, int iter,
                             const float* __restrict__ Mg, const float* __restrict__ Bg,
                             const float* __restrict__ lwg, const float* __restrict__ hwg,
                             K9 kk, float* __restrict__ part, int last) {
    __shared__ unsigned short lu16[HROWF];       // 10752 B (u half-row, bf16)
    __shared__ float tile[CC][264];              // 22176 B (tmp row, w-haloed)
    __shared__ float Ms[CC*CC];                  // 1764 B
    __shared__ float Bs[2*CC], lws[2*CC], hws[2];
    __shared__ float acc[44];
    // total ~35.2 KB -> 4 blocks/CU; grid 1024 = 4 x 256 CUs, single round

    int bid = blockIdx.x;                        // 0..1023
    int xcd = bid & 7, tt = bid >> 3;
    int h  = xcd*64 + (tt >> 1);
    int w0 = (tt & 1) << 8;
    int tx = threadIdx.x;

    for (int i = tx; i < CC*CC; i += 256) Ms[i] = Mg[i];
    if (tx < 2*CC) { Bs[tx] = Bg[tx]; lws[tx] = lwg[tx]; }
    if (tx < 2) hws[tx] = hwg[tx];
    if (tx < 44) acc[tx] = 0.f;

    // stage unaries half-row as bf16 (coalesced float4 reads)
    {
        const float4* src = (const float4*)(unaries + (size_t)h*ROWF + w0*CC);
        ushort4* dst = (ushort4*)lu16;
        #pragma unroll
        for (int j = 0; j < 6; ++j) {
            int idx = j*256 + tx;
            if (idx < HROWF/4) {
                float4 f = src[idx];
                ushort4 o;
                o.x = f_to_bf16(f.x); o.y = f_to_bf16(f.y);
                o.z = f_to_bf16(f.z); o.w = f_to_bf16(f.w);
                dst[idx] = o;
            }
        }
    }

    // stage haloed tmp row tile (coalesced)
    const float* trow = tmp + (size_t)h*WW;
    for (int idx = tx; idx < CC*264; idx += 256) {
        int c = idx / 264;
        int j = idx - c*264;
        int gw = w0 + j - 4;
        tile[c][j] = (gw >= 0 && gw < WW) ? trow[(size_t)c*HWSZ + gw] : 0.f;
    }
    __syncthreads();

    int w = w0 + tx;
    int p = h*WW + w;

    // horizontal blur
    float b[CC];
    #pragma unroll
    for (int c = 0; c < CC; ++c) {
        float a = 0.f;
        #pragma unroll
        for (int t = 0; t < 9; ++t) a += kk.k[t] * tile[c][tx + t];
        b[c] = a;
    }

    // separable norm = s(h)*s(w)
    float sv = 0.f, swn = 0.f;
    #pragma unroll
    for (int t = 0; t < 9; ++t) {
        int hh = h + t - 4; if (hh >= 0 && hh < HH) sv  += kk.k[t];
        int wi = w + t - 4; if (wi >= 0 && wi < WW) swn += kk.k[t];
    }
    float invnorm = 1.f / (sv * swn);

    int idxv = sp_indices[iter];
    int lab  = spT[p];
    float hw0 = hws[0], hw1 = hws[1];

    float qn[CC];
    float qmax = -1e30f;
    #pragma unroll
    for (int c = 0; c < CC; ++c) {
        float pw = 0.f;
        #pragma unroll
        for (int k = 0; k < CC; ++k) pw += Ms[c*CC + k] * b[k];
        pw *= invnorm;

        float smv = sm[(size_t)c*HWSZ + p];
        float qm  = (smv == 0.f) ? 1.f : smv;
        float ft1 = (lab == idxv)     ? Bs[c]      / qm : 0.f;
        float ft2 = (lab == idxv + 1) ? Bs[CC + c] / qm : 0.f;
        float fta = ft1 + ft2;              // masks disjoint
        float att = lws[c]*ft1 + hw0*(1.f - ft1) + lws[CC + c]*fta + hw1*(1.f - fta);

        qn[c] = bf16_to_f(lu16[tx*CC + c]) - pw - att;
        qmax = fmaxf(qmax, qn[c]);
    }

    if (!last) {
        // fused softmax -> sm_{it+1}, in-place (own pixel only)
        float ssum = 0.f;
        #pragma unroll
        for (int c = 0; c < CC; ++c) { qn[c] = expf(qn[c] - qmax); ssum += qn[c]; }
        float inv = 1.f / ssum;
        #pragma unroll
        for (int c = 0; c < CC; ++c) { qn[c] *= inv; sm[(size_t)c*HWSZ + p] = qn[c]; }
        // clique partials for NEXT iteration's B
        int idx2 = sp_indices[iter + 1];
        if (lab == idx2 || lab == idx2 + 1) {
            int mk = (lab == idx2) ? 0 : 1;
            atomicAdd(&acc[42 + mk], 1.f);
            for (int c = 0; c < CC; ++c) atomicAdd(&acc[mk*21 + c], expf(qn[c]));
        }
        __syncthreads();
        if (tx < 44) part[tx*PBLOCKS + bid] = acc[tx];
    } else {
        // write q5 to out in HWC; reuse tile as staging (all tile reads done
        // by every wave only after the barrier below)
        __syncthreads();
        float* lo = &tile[0][0];
        #pragma unroll
        for (int c = 0; c < CC; ++c) lo[tx*CC + c] = qn[c];
        __syncthreads();
        float4* dst = (float4*)(outHWC + (size_t)h*ROWF + w0*CC);
        const float4* srcf = (const float4*)lo;
        #pragma unroll
        for (int j = 0; j < 6; ++j) {
            int idx = j*256 + tx;
            if (idx < HROWF/4) dst[idx] = srcf[idx];
        }
    }
}

extern "C" void kernel_launch(void* const* d_in, const int* in_sizes, int n_in,
                              void* d_out, int out_size, void* d_ws, size_t ws_size,
                              hipStream_t stream) {
    const float* unaries    = (const float*)d_in[0];
    // d_in[1] = rgb (unused by the reference)
    const int*   sp_map     = (const int*)d_in[2];
    const int*   sp_indices = (const int*)d_in[3];
    const float* skw        = (const float*)d_in[4];
    const float* bkw        = (const float*)d_in[5];
    const float* cm         = (const float*)d_in[6];
    const float* lw         = (const float*)d_in[7];
    const float* hwt        = (const float*)d_in[8];
    float* out = (float*)d_out;

    float* ws   = (float*)d_ws;
    float* bufA = ws;                    // sm (stable home, updated in-place)
    float* bufT = ws + CHW;              // tmp (vblur output)
    float* M    = ws + 2*(size_t)CHW;    // 441
    float* Bv   = M + CC*CC;             // 42 (+pad)
    float* part = Bv + 64;               // 44*PBLOCKS (slot-major)
    int*   spT  = (int*)(part + 44*PBLOCKS);   // HWSZ ints

    // 9-tap normalized Gaussian, sigma=3 (fp32, matches reference)
    K9 kk;
    {
        float s = 0.f;
        for (int t = 0; t < 9; ++t) {
            float x = (float)(t - 4) / 3.0f;
            kk.k[t] = expf(-0.5f * x * x);
            s += kk.k[t];
        }
        for (int t = 0; t < 9; ++t) kk.k[t] /= s;
    }

    transpose_sp_kernel<<<HWSZ/256, 256, 0, stream>>>(sp_map, spT);
    precomp_M_kernel<<<2, 256, 0, stream>>>(skw, bkw, cm, M);
    init_sm_kernel<<<PBLOCKS, 256, 0, stream>>>(unaries, bufA, spT, sp_indices, part);

    for (int it = 0; it < NITERS; ++it) {
        finalize_kernel<<<42, 256, 0, stream>>>(part, Bv);        // B_it from part_it
        vblur_kernel<<<CC*1024, 256, 0, stream>>>(bufA, bufT, kk); // sm_it -> tmp
        int last = (it == NITERS - 1);
        final_kernel<<<PBLOCKS, 256, 0, stream>>>(bufT, bufA, out, unaries, spT,
                                                  sp_indices, it, M, Bv, lw, hwt,
                                                  kk, part, last);
    }
}

// Round 9
// 307.790 us; speedup vs baseline: 6.2687x; 6.2687x over previous
//
#include <hip/hip_runtime.h>
#include <cmath>

#define CC 21
#define HH 512
#define WW 512
#define HWSZ (HH*WW)
#define CHW (CC*HWSZ)
#define NITERS 5
#define PBLOCKS 1024          // partial-reduction width (blocks of init_sm/final)
#define ROWF (CC*WW)          // 10752 floats per image row in HWC
#define HROWF (CC*256)        // 5376 floats per half row

struct K9 { float k[9]; };

__device__ __forceinline__ float bf16_to_f(unsigned short v) {
    union { unsigned int i; float f; } cv; cv.i = ((unsigned int)v) << 16; return cv.f;
}
__device__ __forceinline__ unsigned short f_to_bf16(float f) {
    union { float f; unsigned int i; } cv; cv.f = f;
    unsigned int b = cv.i + 0x7FFFu + ((cv.i >> 16) & 1u);   // RNE
    return (unsigned short)(b >> 16);
}

// spT[h*W + w] = sp_map[w*W + h]  (one-time; coalesced mask reads later)
__global__ void transpose_sp_kernel(const int* __restrict__ sp, int* __restrict__ spT) {
    int p = blockIdx.x*256 + threadIdx.x;
    int h = p >> 9, w = p & (WW - 1);
    spT[p] = sp[w*WW + h];
}

// M = CM @ (SKW + BKW)   (both blurs identical since theta_gamma==theta_beta)
__global__ void precomp_M_kernel(const float* __restrict__ skw, const float* __restrict__ bkw,
                                 const float* __restrict__ cm, float* __restrict__ M) {
    int i = blockIdx.x * blockDim.x + threadIdx.x;
    if (i >= CC*CC) return;
    int r = i / CC, k = i - r*CC;
    float a = 0.f;
    for (int j = 0; j < CC; ++j) a += cm[r*CC + j] * (skw[j*CC + k] + bkw[j*CC + k]);
    M[i] = a;
}

// iter-0: sm0 = softmax(u) from LDS-staged unaries half-row + clique partials.
// part layout SLOT-MAJOR: part[t*PBLOCKS + b]; t: 0..20 s1, 21..41 s2, 42 n1, 43 n2
__launch_bounds__(256)
__global__ void init_sm_kernel(const float* __restrict__ unaries, float* __restrict__ sm,
                               const int* __restrict__ spT,
                               const int* __restrict__ sp_indices,
                               float* __restrict__ part) {
    __shared__ __align__(16) float lu[HROWF];
    __shared__ float acc[44];
    int bid = blockIdx.x;
    int h = bid >> 1, w0 = (bid & 1) << 8;
    int tx = threadIdx.x;
    if (tx < 44) acc[tx] = 0.f;
    {
        const float4* src = (const float4*)(unaries + (size_t)h*ROWF + w0*CC);
        float4* dst = (float4*)lu;
        #pragma unroll
        for (int j = 0; j < 6; ++j) {
            int idx = j*256 + tx;
            if (idx < HROWF/4) dst[idx] = src[idx];
        }
    }
    __syncthreads();
    int p = h*WW + w0 + tx;
    float v[CC]; float m = -1e30f;
    #pragma unroll
    for (int c = 0; c < CC; ++c) { v[c] = lu[tx*CC + c]; m = fmaxf(m, v[c]); }
    float s = 0.f;
    #pragma unroll
    for (int c = 0; c < CC; ++c) { v[c] = expf(v[c] - m); s += v[c]; }
    float inv = 1.f / s;
    #pragma unroll
    for (int c = 0; c < CC; ++c) { v[c] *= inv; sm[(size_t)c*HWSZ + p] = v[c]; }

    int idx = sp_indices[0];
    int lab = spT[p];
    if (lab == idx || lab == idx + 1) {
        int mk = (lab == idx) ? 0 : 1;
        atomicAdd(&acc[42 + mk], 1.f);
        for (int c = 0; c < CC; ++c) atomicAdd(&acc[mk*21 + c], expf(v[c]));
    }
    __syncthreads();
    if (tx < 44) part[tx*PBLOCKS + bid] = acc[tx];
}

// 42 blocks; block t sums slot t and count slot 42+(t/21), coalesced.
__launch_bounds__(256)
__global__ void finalize_kernel(const float* __restrict__ part, float* __restrict__ B) {
    __shared__ float rs[256], rn[256];
    int t = blockIdx.x;          // 0..41
    int m = t / 21;
    int tid = threadIdx.x;
    float s = 0.f, n = 0.f;
    for (int b = tid; b < PBLOCKS; b += 256) {
        s += part[t*PBLOCKS + b];
        n += part[(42 + m)*PBLOCKS + b];
    }
    rs[tid] = s; rn[tid] = n;
    __syncthreads();
    for (int off = 128; off > 0; off >>= 1) {
        if (tid < off) { rs[tid] += rs[tid+off]; rn[tid] += rn[tid+off]; }
        __syncthreads();
    }
    if (tid == 0) B[t] = logf((float)HWSZ - rn[0] + rs[0]);
}

// vertical 9-tap blur, zero pad; float4 per thread (4 pixels).
__launch_bounds__(256)
__global__ void vblur_kernel(const float* __restrict__ sm, float* __restrict__ tmp, K9 kk) {
    size_t idx = ((size_t)blockIdx.x*256 + threadIdx.x) << 2;   // element index
    int p = (int)(idx & (HWSZ - 1));
    int h = p >> 9;
    float4 acc = {0.f, 0.f, 0.f, 0.f};
    #pragma unroll
    for (int t = 0; t < 9; ++t) {
        int hh = h + t - 4;
        if (hh >= 0 && hh < HH) {
            float4 v = *(const float4*)(sm + idx + (long)(t - 4)*WW);
            acc.x += kk.k[t]*v.x; acc.y += kk.k[t]*v.y;
            acc.z += kk.k[t]*v.z; acc.w += kk.k[t]*v.w;
        }
    }
    *(float4*)(tmp + idx) = acc;
}

// Fused: hblur (LDS tile from tmp) -> /norm -> M@ -> attachment -> q_new,
// then softmax(q_new) in-place over sm (own-pixel only) + partials for the
// NEXT iteration's B. qn lives in LDS (tile reuse) -> one reg array only.
// Last iter: gather HWC float4s straight from qlds (transposed index).
__launch_bounds__(256)
__global__ void final_kernel(const float* __restrict__ tmp, float* sm,
                             float* __restrict__ outHWC,
                             const float* __restrict__ unaries,
                             const int* __restrict__ spT,
                             const int* __restrict__ sp_indices, int iter,
                             const float* __restrict__ Mg, const float* __restrict__ Bg,
                             const float* __restrict__ lwg, const float* __restrict__ hwg,
                             K9 kk, float* __restrict__ part, int last) {
    __shared__ __align__(16) unsigned short lu16[HROWF];  // 10752 B (u, bf16)
    __shared__ float tile[CC][264];                       // 22176 B
    __shared__ float Ms[CC*CC];
    __shared__ float Bs[2*CC], lws[2*CC], hws[2];
    __shared__ float acc[44];
    // ~35.3 KB -> 4 blocks/CU

    int bid = blockIdx.x;                        // 0..1023
    int xcd = bid & 7, tt = bid >> 3;
    int h  = xcd*64 + (tt >> 1);
    int w0 = (tt & 1) << 8;
    int tx = threadIdx.x;

    for (int i = tx; i < CC*CC; i += 256) Ms[i] = Mg[i];
    if (tx < 2*CC) { Bs[tx] = Bg[tx]; lws[tx] = lwg[tx]; }
    if (tx < 2) hws[tx] = hwg[tx];
    if (tx < 44) acc[tx] = 0.f;

    // stage unaries half-row as bf16 (coalesced float4 reads)
    {
        const float4* src = (const float4*)(unaries + (size_t)h*ROWF + w0*CC);
        ushort4* dst = (ushort4*)lu16;
        #pragma unroll
        for (int j = 0; j < 6; ++j) {
            int idx = j*256 + tx;
            if (idx < HROWF/4) {
                float4 f = src[idx];
                ushort4 o;
                o.x = f_to_bf16(f.x); o.y = f_to_bf16(f.y);
                o.z = f_to_bf16(f.z); o.w = f_to_bf16(f.w);
                dst[idx] = o;
            }
        }
    }

    // stage haloed tmp row tile (coalesced)
    const float* trow = tmp + (size_t)h*WW;
    for (int idx = tx; idx < CC*264; idx += 256) {
        int c = idx / 264;
        int j = idx - c*264;
        int gw = w0 + j - 4;
        tile[c][j] = (gw >= 0 && gw < WW) ? trow[(size_t)c*HWSZ + gw] : 0.f;
    }
    __syncthreads();

    int w = w0 + tx;
    int p = h*WW + w;

    // horizontal blur -> the ONLY per-thread register array
    float b[CC];
    #pragma unroll
    for (int c = 0; c < CC; ++c) {
        float a = 0.f;
        #pragma unroll
        for (int t = 0; t < 9; ++t) a += kk.k[t] * tile[c][tx + t];
        b[c] = a;
    }
    __syncthreads();          // all tile reads done -> safe to reuse as qlds

    float* qlds = &tile[0][0];   // [CC][256] layout, lane-consecutive: no conflicts

    // separable norm = s(h)*s(w)
    float sv = 0.f, swn = 0.f;
    #pragma unroll
    for (int t = 0; t < 9; ++t) {
        int hh = h + t - 4; if (hh >= 0 && hh < HH) sv  += kk.k[t];
        int wi = w + t - 4; if (wi >= 0 && wi < WW) swn += kk.k[t];
    }
    float invnorm = 1.f / (sv * swn);

    int idxv = sp_indices[iter];
    int lab  = spT[p];
    float hw0 = hws[0], hw1 = hws[1];

    float qmax = -1e30f;
    for (int c = 0; c < CC; ++c) {
        float pw = 0.f;
        #pragma unroll
        for (int k = 0; k < CC; ++k) pw += Ms[c*CC + k] * b[k];
        pw *= invnorm;

        float smv = sm[(size_t)c*HWSZ + p];
        float qm  = (smv == 0.f) ? 1.f : smv;
        float ft1 = (lab == idxv)     ? Bs[c]      / qm : 0.f;
        float ft2 = (lab == idxv + 1) ? Bs[CC + c] / qm : 0.f;
        float fta = ft1 + ft2;              // masks disjoint
        float att = lws[c]*ft1 + hw0*(1.f - ft1) + lws[CC + c]*fta + hw1*(1.f - fta);

        float qv = bf16_to_f(lu16[tx*CC + c]) - pw - att;
        qlds[c*256 + tx] = qv;
        qmax = fmaxf(qmax, qv);
    }

    if (!last) {
        // fused softmax -> sm_{it+1}, in-place (own pixel only)
        float ssum = 0.f;
        for (int c = 0; c < CC; ++c) {
            float e = expf(qlds[c*256 + tx] - qmax);
            qlds[c*256 + tx] = e;
            ssum += e;
        }
        float inv = 1.f / ssum;
        int idx2 = sp_indices[iter + 1];
        bool in1 = (lab == idx2), in2 = (lab == idx2 + 1);
        int mk = in1 ? 0 : 1;
        if (in1 | in2) atomicAdd(&acc[42 + mk], 1.f);
        for (int c = 0; c < CC; ++c) {
            float smv = qlds[c*256 + tx] * inv;
            sm[(size_t)c*HWSZ + p] = smv;
            if (in1 | in2) atomicAdd(&acc[mk*21 + c], expf(smv));
        }
        __syncthreads();
        if (tx < 44) part[tx*PBLOCKS + bid] = acc[tx];
    } else {
        // q5 -> out HWC: gather float4s directly from qlds, transposed index.
        __syncthreads();                      // all qlds writes visible
        float4* dst = (float4*)(outHWC + (size_t)h*ROWF + w0*CC);
        #pragma unroll
        for (int j = 0; j < 6; ++j) {
            int idx = j*256 + tx;             // float4 index within half-row
            if (idx < HROWF/4) {
                int e = idx * 4;              // HWC element index: e = pix*CC + c
                float4 o;
                o.x = qlds[(e       % CC)*256 + (e       / CC)];
                o.y = qlds[((e + 1) % CC)*256 + ((e + 1) / CC)];
                o.z = qlds[((e + 2) % CC)*256 + ((e + 2) / CC)];
                o.w = qlds[((e + 3) % CC)*256 + ((e + 3) / CC)];
                dst[idx] = o;
            }
        }
    }
}

extern "C" void kernel_launch(void* const* d_in, const int* in_sizes, int n_in,
                              void* d_out, int out_size, void* d_ws, size_t ws_size,
                              hipStream_t stream) {
    const float* unaries    = (const float*)d_in[0];
    // d_in[1] = rgb (unused by the reference)
    const int*   sp_map     = (const int*)d_in[2];
    const int*   sp_indices = (const int*)d_in[3];
    const float* skw        = (const float*)d_in[4];
    const float* bkw        = (const float*)d_in[5];
    const float* cm         = (const float*)d_in[6];
    const float* lw         = (const float*)d_in[7];
    const float* hwt        = (const float*)d_in[8];
    float* out = (float*)d_out;

    float* ws   = (float*)d_ws;
    float* bufA = ws;                    // sm (stable home, updated in-place)
    float* bufT = ws + CHW;              // tmp (vblur output)
    float* M    = ws + 2*(size_t)CHW;    // 441
    float* Bv   = M + CC*CC;             // 42 (+pad)
    float* part = Bv + 64;               // 44*PBLOCKS (slot-major)
    int*   spT  = (int*)(part + 44*PBLOCKS);   // HWSZ ints

    // 9-tap normalized Gaussian, sigma=3 (fp32, matches reference)
    K9 kk;
    {
        float s = 0.f;
        for (int t = 0; t < 9; ++t) {
            float x = (float)(t - 4) / 3.0f;
            kk.k[t] = expf(-0.5f * x * x);
            s += kk.k[t];
        }
        for (int t = 0; t < 9; ++t) kk.k[t] /= s;
    }

    transpose_sp_kernel<<<HWSZ/256, 256, 0, stream>>>(sp_map, spT);
    precomp_M_kernel<<<2, 256, 0, stream>>>(skw, bkw, cm, M);
    init_sm_kernel<<<PBLOCKS, 256, 0, stream>>>(unaries, bufA, spT, sp_indices, part);

    for (int it = 0; it < NITERS; ++it) {
        finalize_kernel<<<42, 256, 0, stream>>>(part, Bv);          // B_it
        vblur_kernel<<<CHW/1024, 256, 0, stream>>>(bufA, bufT, kk); // sm_it -> tmp
        int last = (it == NITERS - 1);
        final_kernel<<<PBLOCKS, 256, 0, stream>>>(bufT, bufA, out, unaries, spT,
                                                  sp_indices, it, M, Bv, lw, hwt,
                                                  kk, part, last);
    }
}

// Round 10
// 288.056 us; speedup vs baseline: 6.6982x; 1.0685x over previous
//
#include <hip/hip_runtime.h>
#include <cmath>

#define CC 21
#define HH 512
#define WW 512
#define HWSZ (HH*WW)
#define CHW (CC*HWSZ)
#define NITERS 5
#define PBLOCKS 1024          // partial-reduction width
#define ROWF (CC*WW)          // 10752 elems per image row in HWC
#define HROWF (CC*256)        // 5376 elems per half row

struct K9 { float k[9]; };

__device__ __forceinline__ float bf16_to_f(unsigned short v) {
    union { unsigned int i; float f; } cv; cv.i = ((unsigned int)v) << 16; return cv.f;
}
__device__ __forceinline__ unsigned short f_to_bf16(float f) {
    union { float f; unsigned int i; } cv; cv.f = f;
    unsigned int b = cv.i + 0x7FFFu + ((cv.i >> 16) & 1u);   // RNE
    return (unsigned short)(b >> 16);
}
__device__ __forceinline__ float lo_bf(unsigned int u) {
    union { unsigned int i; float f; } cv; cv.i = u << 16; return cv.f;
}
__device__ __forceinline__ float hi_bf(unsigned int u) {
    union { unsigned int i; float f; } cv; cv.i = u & 0xFFFF0000u; return cv.f;
}
__device__ __forceinline__ unsigned int pack2_bf(float a, float b) {
    return (unsigned int)f_to_bf16(a) | ((unsigned int)f_to_bf16(b) << 16);
}

// one-time: unaries (HWC fp32) -> bf16
__global__ void convert_u16_kernel(const float* __restrict__ u, unsigned short* __restrict__ u16) {
    size_t i = ((size_t)blockIdx.x*256 + threadIdx.x) * 4;
    float4 f = *(const float4*)(u + i);
    ushort4 o;
    o.x = f_to_bf16(f.x); o.y = f_to_bf16(f.y);
    o.z = f_to_bf16(f.z); o.w = f_to_bf16(f.w);
    *(ushort4*)(u16 + i) = o;
}

// spT[h*W + w] = sp_map[w*W + h]
__global__ void transpose_sp_kernel(const int* __restrict__ sp, int* __restrict__ spT) {
    int p = blockIdx.x*256 + threadIdx.x;
    int h = p >> 9, w = p & (WW - 1);
    spT[p] = sp[w*WW + h];
}

// M = CM @ (SKW + BKW)
__global__ void precomp_M_kernel(const float* __restrict__ skw, const float* __restrict__ bkw,
                                 const float* __restrict__ cm, float* __restrict__ M) {
    int i = blockIdx.x * blockDim.x + threadIdx.x;
    if (i >= CC*CC) return;
    int r = i / CC, k = i - r*CC;
    float a = 0.f;
    for (int j = 0; j < CC; ++j) a += cm[r*CC + j] * (skw[j*CC + k] + bkw[j*CC + k]);
    M[i] = a;
}

// iter-0: sm0 = softmax(u) -> sm16 (+ fp32 smf & partials at clique-0 pixels)
__launch_bounds__(256)
__global__ void init_sm_kernel(const float* __restrict__ unaries,
                               unsigned short* __restrict__ sm16,
                               float* __restrict__ smf,
                               const int* __restrict__ spT,
                               const int* __restrict__ sp_indices,
                               float* __restrict__ part) {
    __shared__ __align__(16) float lu[HROWF];
    __shared__ float acc[44];
    int bid = blockIdx.x;
    int h = bid >> 1, w0 = (bid & 1) << 8;
    int tx = threadIdx.x;
    if (tx < 44) acc[tx] = 0.f;
    {
        const float4* src = (const float4*)(unaries + (size_t)h*ROWF + w0*CC);
        float4* dst = (float4*)lu;
        #pragma unroll
        for (int j = 0; j < 6; ++j) {
            int idx = j*256 + tx;
            if (idx < HROWF/4) dst[idx] = src[idx];
        }
    }
    __syncthreads();
    int p = h*WW + w0 + tx;
    float v[CC]; float m = -1e30f;
    #pragma unroll
    for (int c = 0; c < CC; ++c) { v[c] = lu[tx*CC + c]; m = fmaxf(m, v[c]); }
    float s = 0.f;
    #pragma unroll
    for (int c = 0; c < CC; ++c) { v[c] = expf(v[c] - m); s += v[c]; }
    float inv = 1.f / s;
    #pragma unroll
    for (int c = 0; c < CC; ++c) { v[c] *= inv; sm16[(size_t)c*HWSZ + p] = f_to_bf16(v[c]); }

    int idx = sp_indices[0];
    int lab = spT[p];
    if (lab == idx || lab == idx + 1) {
        int mk = (lab == idx) ? 0 : 1;
        atomicAdd(&acc[42 + mk], 1.f);
        for (int c = 0; c < CC; ++c) {
            smf[(size_t)c*HWSZ + p] = v[c];
            atomicAdd(&acc[mk*21 + c], expf(v[c]));
        }
    }
    __syncthreads();
    if (tx < 44) part[tx*PBLOCKS + bid] = acc[tx];
}

// 42 blocks; block t sums slot t and count slot 42+(t/21), coalesced.
__launch_bounds__(256)
__global__ void finalize_kernel(const float* __restrict__ part, float* __restrict__ B) {
    __shared__ float rs[256], rn[256];
    int t = blockIdx.x;          // 0..41
    int m = t / 21;
    int tid = threadIdx.x;
    float s = 0.f, n = 0.f;
    for (int b = tid; b < PBLOCKS; b += 256) {
        s += part[t*PBLOCKS + b];
        n += part[(42 + m)*PBLOCKS + b];
    }
    rs[tid] = s; rn[tid] = n;
    __syncthreads();
    for (int off = 128; off > 0; off >>= 1) {
        if (tid < off) { rs[tid] += rs[tid+off]; rn[tid] += rn[tid+off]; }
        __syncthreads();
    }
    if (tid == 0) B[t] = logf((float)HWSZ - rn[0] + rs[0]);
}

// vertical 9-tap blur on bf16, zero pad; 8 pixels/thread (uint4 = 8 bf16).
__launch_bounds__(256)
__global__ void vblur_kernel(const unsigned short* __restrict__ sm16,
                             unsigned short* __restrict__ tmp16, K9 kk) {
    size_t idx = ((size_t)blockIdx.x*256 + threadIdx.x) * 8;
    int p = (int)(idx & (HWSZ - 1));
    int h = p >> 9;
    float a0=0,a1=0,a2=0,a3=0,a4=0,a5=0,a6=0,a7=0;
    const unsigned short* base = sm16 + idx;
    #pragma unroll
    for (int t = 0; t < 9; ++t) {
        int hh = h + t - 4;
        if (hh >= 0 && hh < HH) {
            uint4 v = *(const uint4*)(base + (t - 4)*WW);
            float kt = kk.k[t];
            a0 += kt*lo_bf(v.x); a1 += kt*hi_bf(v.x);
            a2 += kt*lo_bf(v.y); a3 += kt*hi_bf(v.y);
            a4 += kt*lo_bf(v.z); a5 += kt*hi_bf(v.z);
            a6 += kt*lo_bf(v.w); a7 += kt*hi_bf(v.w);
        }
    }
    uint4 o;
    o.x = pack2_bf(a0,a1); o.y = pack2_bf(a2,a3);
    o.z = pack2_bf(a4,a5); o.w = pack2_bf(a6,a7);
    *(uint4*)(tmp16 + idx) = o;
}

// Fused: hblur (bf16 LDS tile) -> /norm -> M@ (scalar-cached global M) ->
// attachment (sparse fp32 smf at clique px; const elsewhere) -> q_new,
// softmax in qlds -> sm16 in-place + next-clique smf/partials.
__launch_bounds__(256)
__global__ void final_kernel(const unsigned short* __restrict__ tmp16,
                             unsigned short* __restrict__ sm16,
                             float* __restrict__ smf,
                             float* __restrict__ outHWC,
                             const unsigned short* __restrict__ u16,
                             const int* __restrict__ spT,
                             const int* __restrict__ sp_indices, int iter,
                             const float* __restrict__ Mg, const float* __restrict__ Bg,
                             const float* __restrict__ lwg, const float* __restrict__ hwg,
                             K9 kk, float* __restrict__ part, int last) {
    __shared__ __align__(16) float qlds[HROWF];            // 21504 B
    __shared__ __align__(16) unsigned short lu16[HROWF];   // 10752 B
    __shared__ float acc[44];
    unsigned short* tile16 = (unsigned short*)qlds;        // [CC][264] = 11088 B alias

    int bid = blockIdx.x;                        // 0..1023
    int xcd = bid & 7, tt = bid >> 3;
    int h  = xcd*64 + (tt >> 1);
    int w0 = (tt & 1) << 8;
    int tx = threadIdx.x;
    if (tx < 44) acc[tx] = 0.f;

    // stage u16 half-row (uint4 copy, 672 quads)
    {
        const uint4* src = (const uint4*)(u16 + (size_t)h*ROWF + w0*CC);
        uint4* dst = (uint4*)lu16;
        #pragma unroll
        for (int j = 0; j < 3; ++j) {
            int idx = j*256 + tx;
            if (idx < HROWF/8) dst[idx] = src[idx];
        }
    }

    // stage haloed bf16 tmp tile
    for (int c = 0; c < CC; ++c) {
        for (int j = tx; j < 264; j += 256) {
            int gw = w0 + j - 4;
            tile16[c*264 + j] = (gw >= 0 && gw < WW)
                ? tmp16[(size_t)c*HWSZ + h*WW + gw] : (unsigned short)0;
        }
    }
    __syncthreads();

    int w = w0 + tx;
    int p = h*WW + w;

    // horizontal blur -> the ONLY per-thread register array
    float b[CC];
    #pragma unroll
    for (int c = 0; c < CC; ++c) {
        float a = 0.f;
        #pragma unroll
        for (int t = 0; t < 9; ++t) a += kk.k[t] * bf16_to_f(tile16[c*264 + tx + t]);
        b[c] = a;
    }
    __syncthreads();          // tile reads done -> qlds region reusable

    // separable norm = s(h)*s(w)
    float sv = 0.f, swn = 0.f;
    #pragma unroll
    for (int t = 0; t < 9; ++t) {
        int hh = h + t - 4; if (hh >= 0 && hh < HH) sv  += kk.k[t];
        int wi = w + t - 4; if (wi >= 0 && wi < WW) swn += kk.k[t];
    }
    float invnorm = 1.f / (sv * swn);

    int idxv = sp_indices[iter];
    int lab  = spT[p];
    bool in1 = (lab == idxv), in2 = (lab == idxv + 1);
    bool incur = in1 | in2;
    float hw0 = hwg[0], hw1 = hwg[1];
    float attc = hw0 + hw1;                  // att for non-clique pixels

    float qmax = -1e30f;
    for (int c = 0; c < CC; ++c) {
        float pw = 0.f;
        #pragma unroll
        for (int k = 0; k < CC; ++k) pw += Mg[c*CC + k] * b[k];   // uniform -> s_load
        pw *= invnorm;

        float att = attc;
        if (incur) {
            float smv = smf[(size_t)c*HWSZ + p];
            float qm  = (smv == 0.f) ? 1.f : smv;
            float ft1 = in1 ? Bg[c]      / qm : 0.f;
            float ft2 = in2 ? Bg[CC + c] / qm : 0.f;
            float fta = ft1 + ft2;
            att = lwg[c]*ft1 + hw0*(1.f - ft1) + lwg[CC + c]*fta + hw1*(1.f - fta);
        }
        float qv = bf16_to_f(lu16[tx*CC + c]) - pw - att;
        qlds[c*256 + tx] = qv;
        qmax = fmaxf(qmax, qv);
    }

    if (!last) {
        float ssum = 0.f;
        for (int c = 0; c < CC; ++c) {
            float e = expf(qlds[c*256 + tx] - qmax);
            qlds[c*256 + tx] = e;
            ssum += e;
        }
        float inv = 1.f / ssum;
        int idx2 = sp_indices[iter + 1];
        bool n1 = (lab == idx2), n2 = (lab == idx2 + 1);
        bool innext = n1 | n2;
        int mk = n1 ? 0 : 1;
        if (innext) atomicAdd(&acc[42 + mk], 1.f);
        for (int c = 0; c < CC; ++c) {
            float smv = qlds[c*256 + tx] * inv;
            sm16[(size_t)c*HWSZ + p] = f_to_bf16(smv);
            if (innext) {
                smf[(size_t)c*HWSZ + p] = smv;
                atomicAdd(&acc[mk*21 + c], expf(smv));
            }
        }
        __syncthreads();
        if (tx < 44) part[tx*PBLOCKS + bid] = acc[tx];
    } else {
        // q5 -> out HWC: gather float4s directly from qlds, transposed index.
        __syncthreads();
        float4* dst = (float4*)(outHWC + (size_t)h*ROWF + w0*CC);
        #pragma unroll
        for (int j = 0; j < 6; ++j) {
            int idx = j*256 + tx;
            if (idx < HROWF/4) {
                int e = idx * 4;              // e = pix*CC + c
                float4 o;
                o.x = qlds[(e       % CC)*256 + (e       / CC)];
                o.y = qlds[((e + 1) % CC)*256 + ((e + 1) / CC)];
                o.z = qlds[((e + 2) % CC)*256 + ((e + 2) / CC)];
                o.w = qlds[((e + 3) % CC)*256 + ((e + 3) / CC)];
                dst[idx] = o;
            }
        }
    }
}

extern "C" void kernel_launch(void* const* d_in, const int* in_sizes, int n_in,
                              void* d_out, int out_size, void* d_ws, size_t ws_size,
                              hipStream_t stream) {
    const float* unaries    = (const float*)d_in[0];
    // d_in[1] = rgb (unused by the reference)
    const int*   sp_map     = (const int*)d_in[2];
    const int*   sp_indices = (const int*)d_in[3];
    const float* skw        = (const float*)d_in[4];
    const float* bkw        = (const float*)d_in[5];
    const float* cm         = (const float*)d_in[6];
    const float* lw         = (const float*)d_in[7];
    const float* hwt        = (const float*)d_in[8];
    float* out = (float*)d_out;

    char* wsb = (char*)d_ws;
    unsigned short* sm16 = (unsigned short*)wsb;                 // CHW bf16 (11 MB)
    unsigned short* tmp16 = sm16 + CHW;                          // CHW bf16
    unsigned short* u16   = tmp16 + CHW;                         // CHW bf16
    float* smf  = (float*)(u16 + CHW);                           // CHW fp32 (sparse use)
    float* M    = smf + CHW;                                     // 441
    float* Bv   = M + CC*CC;                                     // 42 (+pad)
    float* part = Bv + 64;                                       // 44*PBLOCKS
    int*   spT  = (int*)(part + 44*PBLOCKS);                     // HWSZ ints

    // 9-tap normalized Gaussian, sigma=3 (fp32, matches reference)
    K9 kk;
    {
        float s = 0.f;
        for (int t = 0; t < 9; ++t) {
            float x = (float)(t - 4) / 3.0f;
            kk.k[t] = expf(-0.5f * x * x);
            s += kk.k[t];
        }
        for (int t = 0; t < 9; ++t) kk.k[t] /= s;
    }

    convert_u16_kernel<<<CHW/1024, 256, 0, stream>>>(unaries, u16);
    transpose_sp_kernel<<<HWSZ/256, 256, 0, stream>>>(sp_map, spT);
    precomp_M_kernel<<<2, 256, 0, stream>>>(skw, bkw, cm, M);
    init_sm_kernel<<<PBLOCKS, 256, 0, stream>>>(unaries, sm16, smf, spT, sp_indices, part);

    for (int it = 0; it < NITERS; ++it) {
        finalize_kernel<<<42, 256, 0, stream>>>(part, Bv);            // B_it
        vblur_kernel<<<CHW/2048, 256, 0, stream>>>(sm16, tmp16, kk);  // sm_it -> tmp
        int last = (it == NITERS - 1);
        final_kernel<<<PBLOCKS, 256, 0, stream>>>(tmp16, sm16, smf, out, u16, spT,
                                                  sp_indices, it, M, Bv, lw, hwt,
                                                  kk, part, last);
    }
}